// Round 1
// baseline (293.258 us; speedup 1.0000x reference)
//
#include <hip/hip_runtime.h>
#include <math.h>

#define NATOMS 4096
#define FDIM   256
#define NHEAD  8
#define DHEAD  32
#define NGRP   128

__device__ __forceinline__ float silu_f(float x) {
    return x / (1.0f + expf(-x));
}

// ---------------------------------------------------------------------------
// Group offsets: seg is sorted int32 in [0, NGRP). off[g] = lower_bound(seg,g).
// cntf[g] = count of group g as float (bias multiplier for fused segsum+Wo1).
// ---------------------------------------------------------------------------
__global__ void offsets_kernel(const int* __restrict__ seg,
                               int* __restrict__ off,
                               float* __restrict__ cntf) {
    int g = threadIdx.x;  // 0..NGRP-1
    if (g >= NGRP) return;
    auto lb = [&](int val) {
        int lo = 0, hi = NATOMS;
        while (lo < hi) {
            int mid = (lo + hi) >> 1;
            if (seg[mid] < val) lo = mid + 1; else hi = mid;
        }
        return lo;
    };
    int a = lb(g);
    int b = lb(g + 1);
    off[g] = a;
    if (g == NGRP - 1) off[NGRP] = NATOMS;
    cntf[g] = (float)(b - a);
}

// ---------------------------------------------------------------------------
// C[M,Ncols] = A[M,K] @ B[Ncols,K]^T + rowScale(m)*bias[n]   (+ optional silu)
// Both A and B row-major ("NT" gemm, contiguous K). BM=BN=64, BK=16,
// 256 threads, 4x4 micro-tile. Assumes M%64==0, Ncols%64==0, K%16==0.
// ---------------------------------------------------------------------------
__global__ __launch_bounds__(256) void gemm_nt(
    const float* __restrict__ A, const float* __restrict__ B,
    const float* __restrict__ bias, const float* __restrict__ rowScale,
    float* __restrict__ C, int M, int Ncols, int K, int act)
{
    const int BM = 64, BN = 64, BK = 16;
    __shared__ float As[BK][BM + 1];
    __shared__ float Bs[BK][BN + 1];

    int tid = threadIdx.x;
    int bm = blockIdx.y * BM;
    int bn = blockIdx.x * BN;
    int tx = tid & 15;        // 16 cols of threads
    int ty = tid >> 4;        // 16 rows of threads

    int lm = tid >> 2;          // 0..63 (tile row for loads)
    int lk = (tid & 3) << 2;    // 0,4,8,12 (k offset, float4)

    float acc[4][4] = {};

    for (int kt = 0; kt < K; kt += BK) {
        // cooperative loads: 64x16 tile each, float4 per thread
        const float4 av = *(const float4*)(A + (size_t)(bm + lm) * K + kt + lk);
        const float4 bv = *(const float4*)(B + (size_t)(bn + lm) * K + kt + lk);
        As[lk + 0][lm] = av.x; As[lk + 1][lm] = av.y;
        As[lk + 2][lm] = av.z; As[lk + 3][lm] = av.w;
        Bs[lk + 0][lm] = bv.x; Bs[lk + 1][lm] = bv.y;
        Bs[lk + 2][lm] = bv.z; Bs[lk + 3][lm] = bv.w;
        __syncthreads();

#pragma unroll
        for (int kk = 0; kk < BK; ++kk) {
            float a0[4], b0[4];
#pragma unroll
            for (int i = 0; i < 4; ++i) a0[i] = As[kk][ty * 4 + i];
#pragma unroll
            for (int j = 0; j < 4; ++j) b0[j] = Bs[kk][tx * 4 + j];
#pragma unroll
            for (int i = 0; i < 4; ++i)
#pragma unroll
                for (int j = 0; j < 4; ++j)
                    acc[i][j] = fmaf(a0[i], b0[j], acc[i][j]);
        }
        __syncthreads();
    }

#pragma unroll
    for (int i = 0; i < 4; ++i) {
        int m = bm + ty * 4 + i;
        float rs = rowScale ? rowScale[m] : 1.0f;
#pragma unroll
        for (int j = 0; j < 4; ++j) {
            int n = bn + tx * 4 + j;
            float v = acc[i][j] + rs * bias[n];
            if (act) v = silu_f(v);
            C[(size_t)m * Ncols + n] = v;
        }
    }
}

// ---------------------------------------------------------------------------
// Per (group g, head h): Ysum[g, h*32+d] = sum_{i in g} sum_{j in g}
//     silu(q_i . k_j) * v_j[d]
// Block: 256 threads = 8 row-slots (r) x 32 dims (d). Score reduced across
// the 32 d-lanes via shfl_xor (stays within a 32-lane half of the wave).
// ---------------------------------------------------------------------------
__global__ __launch_bounds__(256) void attn_kernel(
    const float* __restrict__ q, const float* __restrict__ k,
    const float* __restrict__ v, const int* __restrict__ off,
    float* __restrict__ Ysum)
{
    int g = blockIdx.x, h = blockIdx.y;
    int base = off[g];
    int n = off[g + 1] - base;

    int tid = threadIdx.x;
    int d = tid & 31;
    int r = tid >> 5;  // 0..7

    __shared__ float red[8][DHEAD + 1];

    const float* qh = q + (size_t)base * FDIM + h * DHEAD;
    const float* kh = k + (size_t)base * FDIM + h * DHEAD;
    const float* vh = v + (size_t)base * FDIM + h * DHEAD;

    float acc = 0.0f;
    for (int i = r; i < n; i += 8) {
        float qd = qh[(size_t)i * FDIM + d];
        for (int j = 0; j < n; ++j) {
            float prod = qd * kh[(size_t)j * FDIM + d];
            // reduce across the 32 d-lanes (butterfly; masks <32 keep halves)
#pragma unroll
            for (int m = 16; m >= 1; m >>= 1)
                prod += __shfl_xor(prod, m, 64);
            float p = prod / (1.0f + expf(-prod));
            acc = fmaf(p, vh[(size_t)j * FDIM + d], acc);
        }
    }

    red[r][d] = acc;
    __syncthreads();
    if (r == 0) {
        float s = 0.0f;
#pragma unroll
        for (int rr = 0; rr < 8; ++rr) s += red[rr][d];
        Ysum[(size_t)g * FDIM + h * DHEAD + d] = s;
    }
}

// ---------------------------------------------------------------------------
extern "C" void kernel_launch(void* const* d_in, const int* in_sizes, int n_in,
                              void* d_out, int out_size, void* d_ws, size_t ws_size,
                              hipStream_t stream) {
    const float* x    = (const float*)d_in[0];
    const int*   eidx = (const int*)  d_in[1];   // [2, N]; seg = row 1
    const float* Wq   = (const float*)d_in[2];
    const float* bq   = (const float*)d_in[3];
    const float* Wk   = (const float*)d_in[4];
    const float* bk   = (const float*)d_in[5];
    const float* Wv   = (const float*)d_in[6];
    const float* bv   = (const float*)d_in[7];
    const float* Wo1  = (const float*)d_in[8];
    const float* bo1  = (const float*)d_in[9];
    const float* Wo2  = (const float*)d_in[10];
    const float* bo2  = (const float*)d_in[11];
    float* out = (float*)d_out;

    const int* seg = eidx + NATOMS;

    // workspace layout (floats)
    const size_t NF = (size_t)NATOMS * FDIM;   // 1,048,576
    const size_t GF = (size_t)NGRP * FDIM;     // 32,768
    float* q    = (float*)d_ws;
    float* k    = q + NF;
    float* v    = k + NF;
    float* Ysum = v + NF;
    float* S    = Ysum + GF;
    float* cntf = S + GF;
    int*   off  = (int*)(cntf + NGRP);

    // 1. group boundaries
    offsets_kernel<<<1, 128, 0, stream>>>(seg, off, cntf);

    // 2. projections q,k,v = x @ W^T + b   [4096,256]x[256,256]
    dim3 gproj(FDIM / 64, NATOMS / 64);
    gemm_nt<<<gproj, 256, 0, stream>>>(x, Wq, bq, nullptr, q, NATOMS, FDIM, FDIM, 0);
    gemm_nt<<<gproj, 256, 0, stream>>>(x, Wk, bk, nullptr, k, NATOMS, FDIM, FDIM, 0);
    gemm_nt<<<gproj, 256, 0, stream>>>(x, Wv, bv, nullptr, v, NATOMS, FDIM, FDIM, 0);

    // 3. block-diagonal attention, fused with per-group row-sum
    dim3 gattn(NGRP, NHEAD);
    attn_kernel<<<gattn, 256, 0, stream>>>(q, k, v, off, Ysum);

    // 4. S = Ysum @ Wo1^T + cnt_g * bo1   [128,256]x[256,256]
    dim3 gsmall(FDIM / 64, NGRP / 64);
    gemm_nt<<<gsmall, 256, 0, stream>>>(Ysum, Wo1, bo1, cntf, S, NGRP, FDIM, FDIM, 0);

    // 5. out = silu(S @ Wo2^T + bo2)
    gemm_nt<<<gsmall, 256, 0, stream>>>(S, Wo2, bo2, nullptr, out, NGRP, FDIM, FDIM, 1);
}

// Round 2
// 146.283 us; speedup vs baseline: 2.0047x; 2.0047x over previous
//
#include <hip/hip_runtime.h>
#include <math.h>

#define NATOMS 4096
#define FDIM   256
#define NHEAD  8
#define DHEAD  32
#define NGRP   128

__device__ __forceinline__ float silu_f(float x) {
    return x / (1.0f + __expf(-x));
}

// ---------------------------------------------------------------------------
// Group offsets: seg is sorted int32 in [0, NGRP). off[g] = lower_bound(seg,g).
// cntf[g] = count of group g as float (bias multiplier for fused segsum+Wo1).
// ---------------------------------------------------------------------------
__global__ void offsets_kernel(const int* __restrict__ seg,
                               int* __restrict__ off,
                               float* __restrict__ cntf) {
    int g = threadIdx.x;  // 0..NGRP-1
    if (g >= NGRP) return;
    auto lb = [&](int val) {
        int lo = 0, hi = NATOMS;
        while (lo < hi) {
            int mid = (lo + hi) >> 1;
            if (seg[mid] < val) lo = mid + 1; else hi = mid;
        }
        return lo;
    };
    int a = lb(g);
    int b = lb(g + 1);
    off[g] = a;
    if (g == NGRP - 1) off[NGRP] = NATOMS;
    cntf[g] = (float)(b - a);
}

// ---------------------------------------------------------------------------
// Fused Q/K/V projection: {q,k,v}[M,N] = x[M,K] @ W{q,k,v}[N,K]^T + b
// BM=BN=64, BK=16, 256 threads, 4x4 micro-tile x 3 outputs.
// ---------------------------------------------------------------------------
__global__ __launch_bounds__(256) void gemm_qkv(
    const float* __restrict__ A,
    const float* __restrict__ W0, const float* __restrict__ W1, const float* __restrict__ W2,
    const float* __restrict__ b0, const float* __restrict__ b1, const float* __restrict__ b2,
    float* __restrict__ C0, float* __restrict__ C1, float* __restrict__ C2)
{
    const int K = FDIM, Ncols = FDIM;
    __shared__ float As[16][68];
    __shared__ float Bs[3][16][68];

    int tid = threadIdx.x;
    int bm = blockIdx.y * 64;
    int bn = blockIdx.x * 64;
    int tx = tid & 15;
    int ty = tid >> 4;
    int lm = tid >> 2;          // 0..63
    int lk = (tid & 3) << 2;    // 0,4,8,12

    const float* Ws[3] = {W0, W1, W2};

    float acc[3][4][4] = {};

    for (int kt = 0; kt < K; kt += 16) {
        const float4 av = *(const float4*)(A + (size_t)(bm + lm) * K + kt + lk);
        As[lk + 0][lm] = av.x; As[lk + 1][lm] = av.y;
        As[lk + 2][lm] = av.z; As[lk + 3][lm] = av.w;
#pragma unroll
        for (int w = 0; w < 3; ++w) {
            const float4 bv = *(const float4*)(Ws[w] + (size_t)(bn + lm) * K + kt + lk);
            Bs[w][lk + 0][lm] = bv.x; Bs[w][lk + 1][lm] = bv.y;
            Bs[w][lk + 2][lm] = bv.z; Bs[w][lk + 3][lm] = bv.w;
        }
        __syncthreads();

#pragma unroll
        for (int kk = 0; kk < 16; ++kk) {
            float4 a = *(const float4*)&As[kk][ty * 4];
            float4 b[3];
#pragma unroll
            for (int w = 0; w < 3; ++w) b[w] = *(const float4*)&Bs[w][kk][tx * 4];
            float ar[4] = {a.x, a.y, a.z, a.w};
#pragma unroll
            for (int w = 0; w < 3; ++w) {
                float br[4] = {b[w].x, b[w].y, b[w].z, b[w].w};
#pragma unroll
                for (int i = 0; i < 4; ++i)
#pragma unroll
                    for (int j = 0; j < 4; ++j)
                        acc[w][i][j] = fmaf(ar[i], br[j], acc[w][i][j]);
            }
        }
        __syncthreads();
    }

    float* Cs[3] = {C0, C1, C2};
    const float* bs[3] = {b0, b1, b2};
#pragma unroll
    for (int w = 0; w < 3; ++w) {
#pragma unroll
        for (int i = 0; i < 4; ++i) {
            int m = bm + ty * 4 + i;
#pragma unroll
            for (int j = 0; j < 4; ++j) {
                int n = bn + tx * 4 + j;
                Cs[w][(size_t)m * Ncols + n] = acc[w][i][j] + bs[w][n];
            }
        }
    }
}

// ---------------------------------------------------------------------------
// Small NT gemm: C[M,N] = A[M,K] @ B[N,K]^T + rowScale(m)*bias[n] (+silu)
// BM=BN=32, BK=32, 256 threads, 2x2 micro-tile. M%32==0, N%32==0, K%32==0.
// ---------------------------------------------------------------------------
__global__ __launch_bounds__(256) void gemm_small(
    const float* __restrict__ A, const float* __restrict__ B,
    const float* __restrict__ bias, const float* __restrict__ rowScale,
    float* __restrict__ C, int M, int Ncols, int K, int act)
{
    __shared__ float As[32][36];
    __shared__ float Bs[32][36];

    int tid = threadIdx.x;
    int bm = blockIdx.y * 32;
    int bn = blockIdx.x * 32;
    int tx = tid & 15;
    int ty = tid >> 4;
    int lm = tid >> 3;          // 0..31
    int lk = (tid & 7) << 2;    // 0..28

    float acc[2][2] = {};

    for (int kt = 0; kt < K; kt += 32) {
        const float4 av = *(const float4*)(A + (size_t)(bm + lm) * K + kt + lk);
        const float4 bv = *(const float4*)(B + (size_t)(bn + lm) * K + kt + lk);
        As[lk + 0][lm] = av.x; As[lk + 1][lm] = av.y;
        As[lk + 2][lm] = av.z; As[lk + 3][lm] = av.w;
        Bs[lk + 0][lm] = bv.x; Bs[lk + 1][lm] = bv.y;
        Bs[lk + 2][lm] = bv.z; Bs[lk + 3][lm] = bv.w;
        __syncthreads();

#pragma unroll
        for (int kk = 0; kk < 32; ++kk) {
            float a0 = As[kk][ty * 2], a1 = As[kk][ty * 2 + 1];
            float c0 = Bs[kk][tx * 2], c1 = Bs[kk][tx * 2 + 1];
            acc[0][0] = fmaf(a0, c0, acc[0][0]);
            acc[0][1] = fmaf(a0, c1, acc[0][1]);
            acc[1][0] = fmaf(a1, c0, acc[1][0]);
            acc[1][1] = fmaf(a1, c1, acc[1][1]);
        }
        __syncthreads();
    }

#pragma unroll
    for (int i = 0; i < 2; ++i) {
        int m = bm + ty * 2 + i;
        float rs = rowScale ? rowScale[m] : 1.0f;
#pragma unroll
        for (int j = 0; j < 2; ++j) {
            int n = bn + tx * 2 + j;
            float vv = acc[i][j] + rs * bias[n];
            if (act) vv = silu_f(vv);
            C[(size_t)m * Ncols + n] = vv;
        }
    }
}

// ---------------------------------------------------------------------------
// Per (group g, head h): Ysum[g, h*32+d] = sum_j w_j * v_j[d],
//   w_j = sum_i silu(q_i . k_j)      (reduce over i first — no per-row output)
// Block: 256 threads. jj = tid&31 owns k-row jj (registers), iq = tid>>5
// splits the i loop 8 ways. q tile in LDS (broadcast b128 reads).
// j-tile JT=32, i-tile IT=64; loops handle arbitrary n.
// ---------------------------------------------------------------------------
#define JT 32
#define IT 64

__global__ __launch_bounds__(256) void attn_kernel(
    const float* __restrict__ q, const float* __restrict__ k,
    const float* __restrict__ v, const int* __restrict__ off,
    float* __restrict__ Ysum)
{
    int g = blockIdx.x, h = blockIdx.y;
    int base = off[g];
    int n = off[g + 1] - base;

    __shared__ float4 qt4[IT * 8];      // 8 KB
    __shared__ float4 vt4[JT * 8];      // 4 KB
    __shared__ float  wred[8][JT];      // 1 KB
    __shared__ float  w[JT];
    __shared__ float  red[8][DHEAD];

    int tid = threadIdx.x;
    int jj = tid & 31;
    int iq = tid >> 5;   // 0..7
    int d = tid & 31;
    int r = tid >> 5;

    const float4* q4 = (const float4*)(q + (size_t)base * FDIM) + h * 8;
    const float4* k4 = (const float4*)(k + (size_t)base * FDIM) + h * 8;
    const float4* v4 = (const float4*)(v + (size_t)base * FDIM) + h * 8;
    // group-local row i lives at [i*64 + c], c in [0,8)

    float accY = 0.0f;

    for (int j0 = 0; j0 < n; j0 += JT) {
        int jt_n = min(JT, n - j0);
        __syncthreads();               // protect vt4/w from previous tile readers
        for (int idx = tid; idx < jt_n * 8; idx += 256)
            vt4[idx] = v4[(size_t)(j0 + (idx >> 3)) * 64 + (idx & 7)];

        float4 kr[8];
        {
            int jrow = (jj < jt_n) ? (j0 + jj) : j0;
#pragma unroll
            for (int c = 0; c < 8; ++c) kr[c] = k4[(size_t)jrow * 64 + c];
        }

        float wpart = 0.0f;
        for (int i0 = 0; i0 < n; i0 += IT) {
            int it_n = min(IT, n - i0);
            __syncthreads();           // protect qt4 from previous i-tile readers
            for (int idx = tid; idx < it_n * 8; idx += 256)
                qt4[idx] = q4[(size_t)(i0 + (idx >> 3)) * 64 + (idx & 7)];
            __syncthreads();
            if (jj < jt_n) {
                for (int ii = iq; ii < it_n; ii += 8) {
                    const float4* qr = &qt4[ii * 8];
                    float s = 0.0f;
#pragma unroll
                    for (int c = 0; c < 8; ++c) {
                        float4 a = qr[c];
                        s = fmaf(a.x, kr[c].x, s);
                        s = fmaf(a.y, kr[c].y, s);
                        s = fmaf(a.z, kr[c].z, s);
                        s = fmaf(a.w, kr[c].w, s);
                    }
                    wpart += silu_f(s);
                }
            }
        }
        wred[iq][jj] = wpart;
        __syncthreads();
        if (tid < JT) {
            float s = 0.0f;
#pragma unroll
            for (int rr = 0; rr < 8; ++rr) s += wred[rr][tid];
            w[tid] = s;
        }
        __syncthreads();
        const float* vts = (const float*)vt4;
        for (int j = r; j < jt_n; j += 8)
            accY = fmaf(w[j], vts[j * 32 + d], accY);
        // next iteration's leading __syncthreads() protects vt4/w
    }

    red[r][d] = accY;
    __syncthreads();
    if (r == 0) {
        float s = 0.0f;
#pragma unroll
        for (int rr = 0; rr < 8; ++rr) s += red[rr][d];
        Ysum[(size_t)g * FDIM + h * DHEAD + d] = s;
    }
}

// ---------------------------------------------------------------------------
extern "C" void kernel_launch(void* const* d_in, const int* in_sizes, int n_in,
                              void* d_out, int out_size, void* d_ws, size_t ws_size,
                              hipStream_t stream) {
    const float* x    = (const float*)d_in[0];
    const int*   eidx = (const int*)  d_in[1];   // [2, N]; seg = row 1
    const float* Wq   = (const float*)d_in[2];
    const float* bq   = (const float*)d_in[3];
    const float* Wk   = (const float*)d_in[4];
    const float* bk   = (const float*)d_in[5];
    const float* Wv   = (const float*)d_in[6];
    const float* bv   = (const float*)d_in[7];
    const float* Wo1  = (const float*)d_in[8];
    const float* bo1  = (const float*)d_in[9];
    const float* Wo2  = (const float*)d_in[10];
    const float* bo2  = (const float*)d_in[11];
    float* out = (float*)d_out;

    const int* seg = eidx + NATOMS;

    const size_t NF = (size_t)NATOMS * FDIM;   // 1,048,576
    const size_t GF = (size_t)NGRP * FDIM;     // 32,768
    float* q    = (float*)d_ws;
    float* k    = q + NF;
    float* v    = k + NF;
    float* Ysum = v + NF;
    float* S    = Ysum + GF;
    float* cntf = S + GF;
    int*   off  = (int*)(cntf + NGRP);

    // 1. group boundaries
    offsets_kernel<<<1, 128, 0, stream>>>(seg, off, cntf);

    // 2. fused projections q,k,v = x @ W^T + b
    dim3 gproj(FDIM / 64, NATOMS / 64);
    gemm_qkv<<<gproj, 256, 0, stream>>>(x, Wq, Wk, Wv, bq, bk, bv, q, k, v);

    // 3. block-diagonal attention fused with per-group row-sum
    dim3 gattn(NGRP, NHEAD);
    attn_kernel<<<gattn, 256, 0, stream>>>(q, k, v, off, Ysum);

    // 4. S = Ysum @ Wo1^T + cnt_g * bo1
    dim3 gsmall(FDIM / 32, NGRP / 32);
    gemm_small<<<gsmall, 256, 0, stream>>>(Ysum, Wo1, bo1, cntf, S, NGRP, FDIM, FDIM, 0);

    // 5. out = silu(S @ Wo2^T + bo2)
    gemm_small<<<gsmall, 256, 0, stream>>>(S, Wo2, bo2, nullptr, out, NGRP, FDIM, FDIM, 1);
}

// Round 3
// 128.213 us; speedup vs baseline: 2.2873x; 1.1409x over previous
//
#include <hip/hip_runtime.h>
#include <math.h>

#define NATOMS 4096
#define FDIM   256
#define NHEAD  8
#define DHEAD  32
#define NGRP   128

typedef __bf16 bf16x8 __attribute__((ext_vector_type(8)));
typedef float  floatx4 __attribute__((ext_vector_type(4)));
typedef unsigned short u16x4 __attribute__((ext_vector_type(4)));

__device__ __forceinline__ float silu_f(float x) {
    return x / (1.0f + __expf(-x));
}

__device__ __forceinline__ unsigned short f2bf(float f) {
    union { float f; unsigned int u; } a;
    a.f = f;
    unsigned int r = a.u + 0x7FFF + ((a.u >> 16) & 1);   // RNE
    return (unsigned short)(r >> 16);
}

// ---------------------------------------------------------------------------
// Prep: convert x -> xb (bf16), Wq|Wk|Wv -> Wb (bf16, [768,256]),
// concat biases -> b_all[768]; block 0 also computes group offsets + counts.
// Unit = one float4. x: 262144 units, each W: 16384 units. Grid = 1216 x 256.
// ---------------------------------------------------------------------------
__global__ __launch_bounds__(256) void prep_kernel(
    const float* __restrict__ x,
    const float* __restrict__ Wq, const float* __restrict__ Wk, const float* __restrict__ Wv,
    const float* __restrict__ bq, const float* __restrict__ bk, const float* __restrict__ bv,
    const int* __restrict__ seg,
    unsigned short* __restrict__ xb, unsigned short* __restrict__ Wb,
    float* __restrict__ b_all, int* __restrict__ off, float* __restrict__ cntf)
{
    int tid = threadIdx.x;
    unsigned int u = blockIdx.x * 256 + tid;

    if (blockIdx.x == 0 && tid < NGRP) {
        int g = tid;
        auto lb = [&](int val) {
            int lo = 0, hi = NATOMS;
            while (lo < hi) {
                int mid = (lo + hi) >> 1;
                if (seg[mid] < val) lo = mid + 1; else hi = mid;
            }
            return lo;
        };
        int a = lb(g);
        int b = lb(g + 1);
        off[g] = a;
        if (g == NGRP - 1) off[NGRP] = NATOMS;
        cntf[g] = (float)(b - a);
    }
    if (blockIdx.x == 1 && tid < 192) {
        // bias concat as float4: 64 per projection
        const float* src = (tid < 64) ? bq : (tid < 128) ? bk : bv;
        int t = tid & 63;
        ((float4*)b_all)[tid] = ((const float4*)src)[t];
    }

    const unsigned int NX4 = 262144;   // x float4 count
    const unsigned int NW4 = 16384;    // per-W float4 count
    float4 fv;
    u16x4* dst;
    if (u < NX4) {
        fv = ((const float4*)x)[u];
        dst = (u16x4*)xb + u;
    } else {
        unsigned int r = u - NX4;
        unsigned int w = r / NW4;       // 0..2
        unsigned int i = r - w * NW4;
        const float* W = (w == 0) ? Wq : (w == 1) ? Wk : Wv;
        fv = ((const float4*)W)[i];
        dst = (u16x4*)Wb + (size_t)w * NW4 + i;
    }
    u16x4 o;
    o[0] = f2bf(fv.x); o[1] = f2bf(fv.y); o[2] = f2bf(fv.z); o[3] = f2bf(fv.w);
    *dst = o;
}

// ---------------------------------------------------------------------------
// QKV projection via MFMA: D[4096,768] = xb @ Wb^T + b_all, scattered into
// contiguous fp32 q|k|v (qkv + (n>>8)*NF + m*256 + (n&255)).
// Block = 256 thr = 4 waves in 2x2; wave tile 32x64 (2 m-frag x 4 n-frag),
// block tile 64x128. No LDS: fragments loaded straight from global (L2-hot).
// Grid: (4096/64, 768/128) = (64, 6).
// ---------------------------------------------------------------------------
__global__ __launch_bounds__(256) void qkv_mfma(
    const unsigned short* __restrict__ xb, const unsigned short* __restrict__ Wb,
    const float* __restrict__ b_all, float* __restrict__ qkv)
{
    int tid = threadIdx.x;
    int lane = tid & 63;
    int ww = tid >> 6;
    int wrow = ww >> 1, wcol = ww & 1;
    int m_base = blockIdx.x * 64 + wrow * 32;
    int n_base = blockIdx.y * 128 + wcol * 64;

    int l15 = lane & 15;
    int quad = lane >> 4;
    int kq = quad * 8;

    floatx4 acc[2][4] = {};

    const unsigned short* arow0 = xb + (size_t)(m_base + l15) * 256 + kq;
    const unsigned short* arow1 = arow0 + 16 * 256;
    const unsigned short* brow[4];
#pragma unroll
    for (int ni = 0; ni < 4; ++ni)
        brow[ni] = Wb + (size_t)(n_base + ni * 16 + l15) * 256 + kq;

#pragma unroll
    for (int ks = 0; ks < 8; ++ks) {
        int ko = ks * 32;
        bf16x8 a0 = *(const bf16x8*)(arow0 + ko);
        bf16x8 a1 = *(const bf16x8*)(arow1 + ko);
#pragma unroll
        for (int ni = 0; ni < 4; ++ni) {
            bf16x8 b = *(const bf16x8*)(brow[ni] + ko);
            acc[0][ni] = __builtin_amdgcn_mfma_f32_16x16x32_bf16(a0, b, acc[0][ni], 0, 0, 0);
            acc[1][ni] = __builtin_amdgcn_mfma_f32_16x16x32_bf16(a1, b, acc[1][ni], 0, 0, 0);
        }
    }

#pragma unroll
    for (int mi = 0; mi < 2; ++mi) {
#pragma unroll
        for (int ni = 0; ni < 4; ++ni) {
            int col_g = n_base + ni * 16 + l15;
            int w = col_g >> 8, c = col_g & 255;
            float bias = b_all[col_g];
            float* outp = qkv + (size_t)w * (NATOMS * FDIM) + c;
#pragma unroll
            for (int r = 0; r < 4; ++r) {
                int row = m_base + mi * 16 + quad * 4 + r;
                outp[(size_t)row * FDIM] = acc[mi][ni][r] + bias;
            }
        }
    }
}

// ---------------------------------------------------------------------------
// Small NT gemm: C[M,N] = A[M,K] @ B[N,K]^T + rowScale(m)*bias[n] (+silu)
// BM=BN=32, BK=32, 256 threads, 2x2 micro-tile.
// ---------------------------------------------------------------------------
__global__ __launch_bounds__(256) void gemm_small(
    const float* __restrict__ A, const float* __restrict__ B,
    const float* __restrict__ bias, const float* __restrict__ rowScale,
    float* __restrict__ C, int M, int Ncols, int K, int act)
{
    __shared__ float As[32][36];
    __shared__ float Bs[32][36];

    int tid = threadIdx.x;
    int bm = blockIdx.y * 32;
    int bn = blockIdx.x * 32;
    int tx = tid & 15;
    int ty = tid >> 4;
    int lm = tid >> 3;
    int lk = (tid & 7) << 2;

    float acc[2][2] = {};

    for (int kt = 0; kt < K; kt += 32) {
        const float4 av = *(const float4*)(A + (size_t)(bm + lm) * K + kt + lk);
        const float4 bv = *(const float4*)(B + (size_t)(bn + lm) * K + kt + lk);
        As[lk + 0][lm] = av.x; As[lk + 1][lm] = av.y;
        As[lk + 2][lm] = av.z; As[lk + 3][lm] = av.w;
        Bs[lk + 0][lm] = bv.x; Bs[lk + 1][lm] = bv.y;
        Bs[lk + 2][lm] = bv.z; Bs[lk + 3][lm] = bv.w;
        __syncthreads();

#pragma unroll
        for (int kk = 0; kk < 32; ++kk) {
            float a0 = As[kk][ty * 2], a1 = As[kk][ty * 2 + 1];
            float c0 = Bs[kk][tx * 2], c1 = Bs[kk][tx * 2 + 1];
            acc[0][0] = fmaf(a0, c0, acc[0][0]);
            acc[0][1] = fmaf(a0, c1, acc[0][1]);
            acc[1][0] = fmaf(a1, c0, acc[1][0]);
            acc[1][1] = fmaf(a1, c1, acc[1][1]);
        }
        __syncthreads();
    }

#pragma unroll
    for (int i = 0; i < 2; ++i) {
        int m = bm + ty * 2 + i;
        float rs = rowScale ? rowScale[m] : 1.0f;
#pragma unroll
        for (int j = 0; j < 2; ++j) {
            int n = bn + tx * 2 + j;
            float vv = acc[i][j] + rs * bias[n];
            if (act) vv = silu_f(vv);
            C[(size_t)m * Ncols + n] = vv;
        }
    }
}

// ---------------------------------------------------------------------------
// Per (group g, head h): Ysum[g, h*32+d] = sum_j w_j * v_j[d],
//   w_j = sum_i silu(q_i . k_j)
// ---------------------------------------------------------------------------
#define JT 32
#define IT 64

__global__ __launch_bounds__(256) void attn_kernel(
    const float* __restrict__ q, const float* __restrict__ k,
    const float* __restrict__ v, const int* __restrict__ off,
    float* __restrict__ Ysum)
{
    int g = blockIdx.x, h = blockIdx.y;
    int base = off[g];
    int end  = off[g + 1];
    // clamp against garbage (rocprof replay may run with poisoned workspace)
    base = min(max(base, 0), NATOMS);
    end  = min(max(end, base), NATOMS);
    int n = end - base;

    __shared__ float4 qt4[IT * 8];
    __shared__ float4 vt4[JT * 8];
    __shared__ float  wred[8][JT];
    __shared__ float  w[JT];
    __shared__ float  red[8][DHEAD];

    int tid = threadIdx.x;
    int jj = tid & 31;
    int iq = tid >> 5;
    int d = tid & 31;
    int r = tid >> 5;

    const float4* q4 = (const float4*)(q + (size_t)base * FDIM) + h * 8;
    const float4* k4 = (const float4*)(k + (size_t)base * FDIM) + h * 8;
    const float4* v4 = (const float4*)(v + (size_t)base * FDIM) + h * 8;

    float accY = 0.0f;

    for (int j0 = 0; j0 < n; j0 += JT) {
        int jt_n = min(JT, n - j0);
        __syncthreads();
        for (int idx = tid; idx < jt_n * 8; idx += 256)
            vt4[idx] = v4[(size_t)(j0 + (idx >> 3)) * 64 + (idx & 7)];

        float4 kr[8];
        {
            int jrow = (jj < jt_n) ? (j0 + jj) : j0;
#pragma unroll
            for (int c = 0; c < 8; ++c) kr[c] = k4[(size_t)jrow * 64 + c];
        }

        float wpart = 0.0f;
        for (int i0 = 0; i0 < n; i0 += IT) {
            int it_n = min(IT, n - i0);
            __syncthreads();
            for (int idx = tid; idx < it_n * 8; idx += 256)
                qt4[idx] = q4[(size_t)(i0 + (idx >> 3)) * 64 + (idx & 7)];
            __syncthreads();
            if (jj < jt_n) {
                for (int ii = iq; ii < it_n; ii += 8) {
                    const float4* qr = &qt4[ii * 8];
                    float s = 0.0f;
#pragma unroll
                    for (int c = 0; c < 8; ++c) {
                        float4 a = qr[c];
                        s = fmaf(a.x, kr[c].x, s);
                        s = fmaf(a.y, kr[c].y, s);
                        s = fmaf(a.z, kr[c].z, s);
                        s = fmaf(a.w, kr[c].w, s);
                    }
                    wpart += silu_f(s);
                }
            }
        }
        wred[iq][jj] = wpart;
        __syncthreads();
        if (tid < JT) {
            float s = 0.0f;
#pragma unroll
            for (int rr = 0; rr < 8; ++rr) s += wred[rr][tid];
            w[tid] = s;
        }
        __syncthreads();
        const float* vts = (const float*)vt4;
        for (int j = r; j < jt_n; j += 8)
            accY = fmaf(w[j], vts[j * 32 + d], accY);
    }

    red[r][d] = accY;
    __syncthreads();
    if (r == 0) {
        float s = 0.0f;
#pragma unroll
        for (int rr = 0; rr < 8; ++rr) s += red[rr][d];
        Ysum[(size_t)g * FDIM + h * DHEAD + d] = s;
    }
}

// ---------------------------------------------------------------------------
extern "C" void kernel_launch(void* const* d_in, const int* in_sizes, int n_in,
                              void* d_out, int out_size, void* d_ws, size_t ws_size,
                              hipStream_t stream) {
    const float* x    = (const float*)d_in[0];
    const int*   eidx = (const int*)  d_in[1];
    const float* Wq   = (const float*)d_in[2];
    const float* bq   = (const float*)d_in[3];
    const float* Wk   = (const float*)d_in[4];
    const float* bk   = (const float*)d_in[5];
    const float* Wv   = (const float*)d_in[6];
    const float* bv   = (const float*)d_in[7];
    const float* Wo1  = (const float*)d_in[8];
    const float* bo1  = (const float*)d_in[9];
    const float* Wo2  = (const float*)d_in[10];
    const float* bo2  = (const float*)d_in[11];
    float* out = (float*)d_out;

    const int* seg = eidx + NATOMS;

    const size_t NF = (size_t)NATOMS * FDIM;   // 1,048,576
    const size_t GF = (size_t)NGRP * FDIM;     // 32,768

    float* q     = (float*)d_ws;               // qkv contiguous: q|k|v
    float* k     = q + NF;
    float* v     = k + NF;
    float* Ysum  = v + NF;
    float* S     = Ysum + GF;
    float* cntf  = S + GF;                     // 128
    float* b_all = cntf + NGRP;                // 768
    int*   off   = (int*)(b_all + 768);        // 129 ints, pad to 160
    unsigned short* xb = (unsigned short*)((float*)off + 160);  // NF bf16
    unsigned short* Wb = xb + NF;              // 768*256 bf16

    // 1. prep: bf16 conversions + bias concat + group offsets
    prep_kernel<<<1216, 256, 0, stream>>>(x, Wq, Wk, Wv, bq, bk, bv, seg,
                                          xb, Wb, b_all, off, cntf);

    // 2. fused QKV projection (bf16 MFMA)
    dim3 gproj(NATOMS / 64, 768 / 128);
    qkv_mfma<<<gproj, 256, 0, stream>>>(xb, Wb, b_all, q);

    // 3. block-diagonal attention fused with per-group row-sum
    dim3 gattn(NGRP, NHEAD);
    attn_kernel<<<gattn, 256, 0, stream>>>(q, k, v, off, Ysum);

    // 4. S = Ysum @ Wo1^T + cnt_g * bo1
    dim3 gsmall(FDIM / 32, NGRP / 32);
    gemm_small<<<gsmall, 256, 0, stream>>>(Ysum, Wo1, bo1, cntf, S, NGRP, FDIM, FDIM, 0);

    // 5. out = silu(S @ Wo2^T + bo2)
    gemm_small<<<gsmall, 256, 0, stream>>>(S, Wo2, bo2, nullptr, out, NGRP, FDIM, FDIM, 1);
}